// Round 5
// baseline (786.393 us; speedup 1.0000x reference)
//
#include <hip/hip_runtime.h>

#define NB_ 5   // N_BASIS
#define MD_ 5   // MAX_DELAY

// ---------------------------------------------------------------------------
// CSR build (per launch): edges bucketed by window-slot key
//   key(e) = (MD-1 - d)*bitstride + n   where pre_idx[e] = d*N + n
// so at step t the slot's spike bit is  zbits[t*words32 + (key>>5)] >> (key&31).
// ---------------------------------------------------------------------------

__global__ __launch_bounds__(256) void hist_kernel(
    const int* __restrict__ pre_idx, int* __restrict__ cnt,
    int E, int N, int bitstride)
{
    int e = blockIdx.x * blockDim.x + threadIdx.x;
    if (e >= E) return;
    int pre = pre_idx[e];
    int d = pre / N;
    int n = pre - d * N;
    atomicAdd(&cnt[(MD_ - 1 - d) * bitstride + n], 1);
}

// Tile-wise exclusive scan. Each block scans SCAN_TILE=1024 items (4/thread),
// writes local-exclusive values to out[], and its tile total to partials[].
// Reused (with partials=nullptr, 1 block, in-place) to scan the partials.
#define SCAN_TILE 1024
__global__ __launch_bounds__(256) void scan_tiles_kernel(
    const int* __restrict__ in, int* __restrict__ out,
    int* __restrict__ partials, int NS)
{
    __shared__ int lds[256];
    int base = blockIdx.x * SCAN_TILE + threadIdx.x * 4;
    int v[4]; int s = 0;
    #pragma unroll
    for (int k = 0; k < 4; ++k) {
        int i = base + k;
        v[k] = (i < NS) ? in[i] : 0;
        s += v[k];
    }
    lds[threadIdx.x] = s;
    __syncthreads();
    int x = s;
    for (int off = 1; off < 256; off <<= 1) {
        int y = (threadIdx.x >= off) ? lds[threadIdx.x - off] : 0;
        __syncthreads();
        x += y;
        lds[threadIdx.x] = x;
        __syncthreads();
    }
    if (partials && threadIdx.x == 255) partials[blockIdx.x] = x;  // tile total
    int run = x - s;   // exclusive prefix of this thread's 4 items
    #pragma unroll
    for (int k = 0; k < 4; ++k) {
        int i = base + k;
        if (i < NS) out[i] = run;
        run += v[k];
    }
}

__global__ __launch_bounds__(256) void scan_addback_kernel(
    int* __restrict__ row_ptr, const int* __restrict__ partials, int NS)
{
    int i = blockIdx.x * blockDim.x + threadIdx.x;
    if (i < NS) row_ptr[i] += partials[i >> 10];   // tile = i / SCAN_TILE
}

// Scatter edge ids; atomicAdd turns row_ptr[s] into the END of row s,
// so row s = [ s? row_ptr[s-1] : 0 , row_ptr[s] ).
__global__ __launch_bounds__(256) void scatter_kernel(
    const int* __restrict__ pre_idx, int* __restrict__ row_ptr,
    int* __restrict__ sortedEid, int E, int N, int bitstride)
{
    int e = blockIdx.x * blockDim.x + threadIdx.x;
    if (e >= E) return;
    int pre = pre_idx[e];
    int d = pre / N;
    int n = pre - d * N;
    int key = (MD_ - 1 - d) * bitstride + n;
    int pos = atomicAdd(&row_ptr[key], 1);
    sortedEid[pos] = e;
}

// ---------------------------------------------------------------------------
// Per-step kernels
// ---------------------------------------------------------------------------

// One thread per window slot; only firing slots touch their edge list.
__global__ __launch_bounds__(256) void edge_csr_kernel(
    const unsigned int* __restrict__ zw,   // zbits + t*words32 (5-row window)
    const int* __restrict__ row_ptr,       // end-pointers (post-scatter)
    const int* __restrict__ sortedEid,
    const int* __restrict__ post_idx,
    const float* __restrict__ weights,
    const float* __restrict__ edge_basis,
    float* __restrict__ i_rec,
    int NS)
{
    int s = blockIdx.x * blockDim.x + threadIdx.x;
    if (s >= NS) return;
    unsigned int w = zw[s >> 5];
    if (!((w >> (s & 31)) & 1u)) return;
    int start = (s > 0) ? row_ptr[s - 1] : 0;
    int end   = row_ptr[s];
    for (int i = start; i < end; ++i) {
        int e = sortedEid[i];
        float wt = weights[e];
        int b = post_idx[e] * NB_;
        const float* bs = edge_basis + (size_t)e * NB_;
        #pragma unroll
        for (int k = 0; k < NB_; ++k)
            atomicAdd(&i_rec[b + k], wt * bs[k]);
    }
}

__global__ __launch_bounds__(256) void neuron_kernel(
    const float* __restrict__ x_t,        // ext_input + t*n5
    float*       __restrict__ psc,
    float*       __restrict__ i_rec,
    const float* __restrict__ syn_decay,
    const float* __restrict__ psc_initial,
    const float* __restrict__ decay,
    const float* __restrict__ current_factor,
    const float* __restrict__ gathered_g,
    const float* __restrict__ v_th,
    const float* __restrict__ v_reset,
    const float* __restrict__ normalizer,
    const float* __restrict__ t_ref,
    const float* __restrict__ exp_dt_k,   // (N,2)
    const float* __restrict__ asc_amps,   // (N,2)
    float*       __restrict__ v,
    float*       __restrict__ r,
    float*       __restrict__ asc,        // (N,2)
    const int*   __restrict__ scnt_t,     // scnt + t (5-slot window counts)
    int*         __restrict__ scnt_new,   // scnt + t + MD
    unsigned int* __restrict__ zrow_prev, // zbits + (t+MD-1)*words32
    unsigned int* __restrict__ zrow_new,  // zbits + (t+MD)*words32
    float*       __restrict__ out_t,      // out + t*N
    int N)
{
    int n = blockIdx.x * blockDim.x + threadIdx.x;
    bool has = (n < N);

    int scw = scnt_t[0] + scnt_t[1] + scnt_t[2] + scnt_t[3] + scnt_t[4];

    float z = 0.0f;
    if (has) {
        const float* x  = x_t + n * NB_;
        float*       pp = psc + n * NB_;
        float ic = 0.0f;
        if (scw > 0) {
            float* ir = i_rec + n * NB_;
            #pragma unroll
            for (int k = 0; k < NB_; ++k) {
                float pv = pp[k] * syn_decay[n * NB_ + k]
                         + (ir[k] + x[k]) * psc_initial[n * NB_ + k];
                pp[k] = pv;
                ir[k] = 0.0f;
                ic += pv;
            }
        } else {
            #pragma unroll
            for (int k = 0; k < NB_; ++k) {
                float pv = pp[k] * syn_decay[n * NB_ + k]
                         + (0.0f + x[k]) * psc_initial[n * NB_ + k];
                pp[k] = pv;
                ic += pv;
            }
        }

        // prev-step spike from the bit row (avoids an N-float array)
        unsigned int pw = zrow_prev[n >> 5];
        float pz = ((pw >> (n & 31)) & 1u) ? 1.0f : 0.0f;

        float a0 = exp_dt_k[2 * n]     * asc[2 * n]     + pz * asc_amps[2 * n];
        float a1 = exp_dt_k[2 * n + 1] * asc[2 * n + 1] + pz * asc_amps[2 * n + 1];
        asc[2 * n]     = a0;
        asc[2 * n + 1] = a1;

        float c1 = ic + (a0 + a1) + gathered_g[n];
        float nv = decay[n] * v[n] + current_factor[n] * c1;
        if (pz > 0.5f) nv = v_reset[n];

        float vsc = (nv - v_th[n]) / normalizer[n];
        z = (vsc > 0.0f) ? 1.0f : 0.0f;
        float rr = r[n];
        if (rr > 0.0f) z = 0.0f;

        r[n] = fmaxf(rr + z * t_ref[n] - 1.0f, 0.0f);   // DT = 1.0
        v[n] = nv;
        out_t[n] = z;
    }

    // bit-pack this step's spikes: one u64 store per wave
    unsigned long long m = __ballot(z != 0.0f);
    int wv = (blockIdx.x * blockDim.x + threadIdx.x) >> 6;
    if ((threadIdx.x & 63) == 0 && (wv << 6) < N) {
        *(unsigned long long*)(zrow_new + (wv << 1)) = m;
        if (m) atomicAdd(scnt_new, __popcll(m));
    }
}

// ---------------------------------------------------------------------------
// Launcher
// ---------------------------------------------------------------------------

extern "C" void kernel_launch(void* const* d_in, const int* in_sizes, int n_in,
                              void* d_out, int out_size, void* d_ws, size_t ws_size,
                              hipStream_t stream)
{
    const float* weights        = (const float*)d_in[0];
    const float* edge_basis     = (const float*)d_in[1];
    const float* ext_input      = (const float*)d_in[2];
    const float* decay          = (const float*)d_in[3];
    const float* current_factor = (const float*)d_in[4];
    const float* gathered_g     = (const float*)d_in[5];
    const float* v_th           = (const float*)d_in[6];
    const float* v_reset        = (const float*)d_in[7];
    const float* normalizer     = (const float*)d_in[8];
    const float* t_ref          = (const float*)d_in[9];
    const float* exp_dt_k       = (const float*)d_in[10];
    const float* asc_amps       = (const float*)d_in[11];
    const float* syn_decay      = (const float*)d_in[12];
    const float* psc_initial    = (const float*)d_in[13];
    const int*   pre_idx        = (const int*)d_in[14];
    const int*   post_idx       = (const int*)d_in[15];

    const int E  = in_sizes[0];
    const int N  = in_sizes[3];
    const int n5 = N * NB_;
    const int T  = in_sizes[2] / n5;          // B = 1

    const int words64   = (N + 63) / 64;      // 782
    const int words32   = words64 * 2;        // 1564
    const int bitstride = words32 * 32;       // 50048
    const int NS        = MD_ * bitstride;    // 250240 slots

    float* out = (float*)d_out;

    // ---- workspace layout --------------------------------------------------
    // zero group (one memset): [cnt NS | i_rec n5 | psc n5 | r N | asc 2N |
    //                           scnt T+MD | zbits head MD*words32]
    char* wsb = (char*)d_ws;
    size_t o = 0;
    int*   cnt    = (int*)(wsb + o);  o += (size_t)NS * 4;
    float* i_rec  = (float*)(wsb + o); o += (size_t)n5 * 4;
    float* psc    = (float*)(wsb + o); o += (size_t)n5 * 4;
    float* r      = (float*)(wsb + o); o += (size_t)N * 4;
    float* asc    = (float*)(wsb + o); o += (size_t)2 * N * 4;
    int*   scnt   = (int*)(wsb + o);  o += (size_t)(T + MD_) * 4;
    o = (o + 15) & ~(size_t)15;
    unsigned int* zbits = (unsigned int*)(wsb + o);
    size_t zero_bytes = o + (size_t)MD_ * words32 * 4;   // through zbits head
    o += (size_t)(T + MD_) * words32 * 4;
    o = (o + 15) & ~(size_t)15;
    float* v       = (float*)(wsb + o); o += (size_t)N * 4;
    int*   row_ptr = (int*)(wsb + o);   o += (size_t)(NS + 1) * 4;
    int*   sortedEid = (int*)(wsb + o); o += (size_t)E * 4;
    int*   partials  = (int*)(wsb + o); o += 256 * 4;

    // ---- setup (every launch: graph replays everything) --------------------
    hipMemsetAsync(d_ws, 0, zero_bytes, stream);
    hipMemcpyAsync(v, v_reset, (size_t)N * 4, hipMemcpyDeviceToDevice, stream);

    const int eblk = (E + 255) / 256;
    hist_kernel<<<eblk, 256, 0, stream>>>(pre_idx, cnt, E, N, bitstride);

    const int ntilesA = (NS + SCAN_TILE - 1) / SCAN_TILE;   // 245
    scan_tiles_kernel<<<ntilesA, 256, 0, stream>>>(cnt, row_ptr, partials, NS);
    scan_tiles_kernel<<<1, 256, 0, stream>>>(partials, partials, (int*)nullptr, ntilesA);
    scan_addback_kernel<<<(NS + 255) / 256, 256, 0, stream>>>(row_ptr, partials, NS);
    scatter_kernel<<<eblk, 256, 0, stream>>>(pre_idx, row_ptr, sortedEid, E, N, bitstride);

    // ---- time loop ----------------------------------------------------------
    const int sblk = (NS + 255) / 256;   // 978
    const int nblk = (N + 255) / 256;    // 196
    for (int t = 0; t < T; ++t) {
        edge_csr_kernel<<<sblk, 256, 0, stream>>>(
            zbits + (size_t)t * words32,
            row_ptr, sortedEid, post_idx, weights, edge_basis, i_rec, NS);

        neuron_kernel<<<nblk, 256, 0, stream>>>(
            ext_input + (size_t)t * n5,
            psc, i_rec, syn_decay, psc_initial,
            decay, current_factor, gathered_g,
            v_th, v_reset, normalizer, t_ref,
            exp_dt_k, asc_amps,
            v, r, asc,
            scnt + t, scnt + t + MD_,
            zbits + (size_t)(t + MD_ - 1) * words32,
            zbits + (size_t)(t + MD_) * words32,
            out + (size_t)t * N,
            N);
    }
}

// Round 6
// 531.557 us; speedup vs baseline: 1.4794x; 1.4794x over previous
//
#include <hip/hip_runtime.h>

#define NB_ 5      // N_BASIS
#define MD_ 5      // MAX_DELAY
#define CSLOTS 512 // slots per coarse bucket (power of 2)
#define CH 8192    // edges per block in partition passes

// ---------------------------------------------------------------------------
// Build (per launch): two-pass counting sort of edges by window-slot key
//   key(e) = (MD-1-d)*bitstride + n,  pre_idx[e] = d*N + n
// Final edgeDat[i] (32B, 2x uint4): {post, w*b0, w*b1, w*b2 | w*b3, w*b4, localslot, 0}
// row_ptr[s] = inclusive end of slot s's run in edgeDat.
// ---------------------------------------------------------------------------

__global__ __launch_bounds__(256) void repack_kernel(
    const float* __restrict__ decay, const float* __restrict__ cf,
    const float* __restrict__ g,     const float* __restrict__ vth,
    const float* __restrict__ vrst,  const float* __restrict__ nrm,
    const float* __restrict__ tref,  const float* __restrict__ ek,
    const float* __restrict__ am,    const float* __restrict__ v_reset,
    float4* __restrict__ pk, float* __restrict__ v, int N)
{
    int n = blockIdx.x * blockDim.x + threadIdx.x;
    if (n >= N) return;
    pk[3 * n]     = make_float4(decay[n], cf[n], g[n], vth[n]);
    pk[3 * n + 1] = make_float4(vrst[n], nrm[n], tref[n], ek[2 * n]);
    pk[3 * n + 2] = make_float4(ek[2 * n + 1], am[2 * n], am[2 * n + 1], 0.0f);
    v[n] = v_reset[n];
}

__global__ __launch_bounds__(256) void coarse_hist_kernel(
    const int* __restrict__ pre_idx, int* __restrict__ chist,
    int E, int N, int bitstride)
{
    __shared__ int cntL[512];
    int t = threadIdx.x;
    cntL[t] = 0; cntL[t + 256] = 0;
    __syncthreads();
    int e0 = blockIdx.x * CH;
    int e1 = min(e0 + CH, E);
    for (int e = e0 + t; e < e1; e += 256) {
        int pre = pre_idx[e];
        int d = pre / N;
        int key = (MD_ - 1 - d) * bitstride + (pre - d * N);
        atomicAdd(&cntL[key >> 9], 1);
    }
    __syncthreads();
    for (int b = t; b < 512; b += 256)
        if (cntL[b]) atomicAdd(&chist[b], cntL[b]);
}

// 1 block: inclusive scan of chist[0..NC) -> coarse_base[1..NC], coarse_ptr=excl
__global__ __launch_bounds__(256) void scan_coarse_kernel(
    const int* __restrict__ chist, int* __restrict__ coarse_base,
    int* __restrict__ coarse_ptr, int NC)
{
    __shared__ int tmp[256];
    int t = threadIdx.x;
    int i0 = 2 * t, i1 = 2 * t + 1;
    int a = (i0 < NC) ? chist[i0] : 0;
    int b = (i1 < NC) ? chist[i1] : 0;
    int s = a + b;
    tmp[t] = s;
    __syncthreads();
    for (int off = 1; off < 256; off <<= 1) {
        int y = (t >= off) ? tmp[t - off] : 0;
        __syncthreads();
        tmp[t] += y;
        __syncthreads();
    }
    int ep = tmp[t] - s;                 // exclusive prefix of pair
    if (t == 0) coarse_base[0] = 0;
    if (i0 < NC) { coarse_ptr[i0] = ep;     coarse_base[i0 + 1] = ep + a; }
    if (i1 < NC) { coarse_ptr[i1] = ep + a; coarse_base[i1 + 1] = ep + s; }
}

__global__ __launch_bounds__(256) void partition_kernel(
    const int*   __restrict__ pre_idx,
    const float* __restrict__ weights,
    const int*   __restrict__ post_idx,
    const float* __restrict__ edge_basis,
    int* __restrict__ coarse_ptr,
    uint4* __restrict__ part,
    int E, int N, int bitstride)
{
    __shared__ int cntL[512];
    __shared__ int posL[512];
    int t = threadIdx.x;
    cntL[t] = 0; cntL[t + 256] = 0;
    __syncthreads();
    int e0 = blockIdx.x * CH;
    int e1 = min(e0 + CH, E);
    for (int e = e0 + t; e < e1; e += 256) {
        int pre = pre_idx[e];
        int d = pre / N;
        int key = (MD_ - 1 - d) * bitstride + (pre - d * N);
        atomicAdd(&cntL[key >> 9], 1);
    }
    __syncthreads();
    for (int b = t; b < 512; b += 256)
        posL[b] = cntL[b] ? atomicAdd(&coarse_ptr[b], cntL[b]) : 0;
    __syncthreads();
    for (int e = e0 + t; e < e1; e += 256) {
        int pre = pre_idx[e];
        int d = pre / N;
        int key = (MD_ - 1 - d) * bitstride + (pre - d * N);
        int b = key >> 9, ls = key & (CSLOTS - 1);
        float w = weights[e];
        const float* bs = edge_basis + (size_t)e * NB_;
        int p = atomicAdd(&posL[b], 1);
        uint4 q0, q1;
        q0.x = (unsigned)post_idx[e];
        q0.y = __float_as_uint(w * bs[0]);
        q0.z = __float_as_uint(w * bs[1]);
        q0.w = __float_as_uint(w * bs[2]);
        q1.x = __float_as_uint(w * bs[3]);
        q1.y = __float_as_uint(w * bs[4]);
        q1.z = (unsigned)ls;
        q1.w = 0u;
        part[2 * (size_t)p]     = q0;
        part[2 * (size_t)p + 1] = q1;
    }
}

// one block per coarse bucket: LDS counting sort over CSLOTS local slots
__global__ __launch_bounds__(256) void bucket_sort_kernel(
    const int* __restrict__ coarse_base,
    const uint4* __restrict__ part,
    uint4* __restrict__ edgeDat,
    int* __restrict__ row_ptr, int NS)
{
    __shared__ int h[CSLOTS];
    __shared__ int pos[CSLOTS];
    __shared__ int tmp[256];
    int c = blockIdx.x, t = threadIdx.x;
    int lo = coarse_base[c], hi = coarse_base[c + 1];
    h[2 * t] = 0; h[2 * t + 1] = 0;
    __syncthreads();
    const unsigned* pw = (const unsigned*)part;
    for (int i = lo + t; i < hi; i += 256)
        atomicAdd(&h[pw[(size_t)i * 8 + 6]], 1);
    __syncthreads();
    int a = h[2 * t], b = h[2 * t + 1], s = a + b;
    tmp[t] = s;
    __syncthreads();
    for (int off = 1; off < 256; off <<= 1) {
        int y = (t >= off) ? tmp[t - off] : 0;
        __syncthreads();
        tmp[t] += y;
        __syncthreads();
    }
    int ep = tmp[t] - s;
    pos[2 * t]     = lo + ep;
    pos[2 * t + 1] = lo + ep + a;
    int base_slot = c * CSLOTS;
    if (base_slot + 2 * t     < NS) row_ptr[base_slot + 2 * t]     = lo + ep + a;
    if (base_slot + 2 * t + 1 < NS) row_ptr[base_slot + 2 * t + 1] = lo + ep + s;
    __syncthreads();
    for (int i = lo + t; i < hi; i += 256) {
        uint4 q0 = part[2 * (size_t)i], q1 = part[2 * (size_t)i + 1];
        int dst = atomicAdd(&pos[q1.z], 1);
        edgeDat[2 * (size_t)dst]     = q0;
        edgeDat[2 * (size_t)dst + 1] = q1;
    }
}

// ---------------------------------------------------------------------------
// Per-step kernels
// ---------------------------------------------------------------------------

__global__ __launch_bounds__(256) void edge_step_kernel(
    const unsigned* __restrict__ zw,      // zbits + t*words32
    const int* __restrict__ row_ptr,
    const uint4* __restrict__ dat,
    float* __restrict__ i_rec,
    const int* __restrict__ scnt_t,
    int NS)
{
    __shared__ int sc;
    if (threadIdx.x == 0)
        sc = scnt_t[0] + scnt_t[1] + scnt_t[2] + scnt_t[3] + scnt_t[4];
    __syncthreads();
    if (sc == 0) return;
    int s = blockIdx.x * blockDim.x + threadIdx.x;
    if (s >= NS) return;
    if (!((zw[s >> 5] >> (s & 31)) & 1u)) return;
    int start = s ? row_ptr[s - 1] : 0;
    int end   = row_ptr[s];
    for (int i = start; i < end; ++i) {
        uint4 q0 = dat[2 * (size_t)i], q1 = dat[2 * (size_t)i + 1];
        float* ir = i_rec + (size_t)q0.x * NB_;
        atomicAdd(ir + 0, __uint_as_float(q0.y));
        atomicAdd(ir + 1, __uint_as_float(q0.z));
        atomicAdd(ir + 2, __uint_as_float(q0.w));
        atomicAdd(ir + 3, __uint_as_float(q1.x));
        atomicAdd(ir + 4, __uint_as_float(q1.y));
    }
}

__global__ __launch_bounds__(256) void neuron_kernel(
    const float* __restrict__ x_t,
    float*       __restrict__ psc,
    float*       __restrict__ i_rec,
    const float* __restrict__ syn_decay,
    const float* __restrict__ psc_initial,
    const float4* __restrict__ pk,        // {decay,cf,g,vth}{vrst,nrm,tref,ek0}{ek1,am0,am1,_}
    float* __restrict__ v,
    float* __restrict__ r,
    float* __restrict__ asc,
    const int* __restrict__ scnt_t,
    int*       __restrict__ scnt_new,
    const unsigned* __restrict__ zrow_prev,
    unsigned*       __restrict__ zrow_new,
    float* __restrict__ out_t,
    int N)
{
    int n = blockIdx.x * blockDim.x + threadIdx.x;
    bool has = (n < N);
    int scw = scnt_t[0] + scnt_t[1] + scnt_t[2] + scnt_t[3] + scnt_t[4];

    float z = 0.0f;
    if (has) {
        float4 P0 = pk[3 * n], P1 = pk[3 * n + 1], P2 = pk[3 * n + 2];
        const float* x  = x_t + n * NB_;
        float*       pp = psc + n * NB_;
        float ic = 0.0f;
        if (scw > 0) {
            float* ir = i_rec + n * NB_;
            #pragma unroll
            for (int k = 0; k < NB_; ++k) {
                float pv = pp[k] * syn_decay[n * NB_ + k]
                         + (ir[k] + x[k]) * psc_initial[n * NB_ + k];
                pp[k] = pv;
                ir[k] = 0.0f;
                ic += pv;
            }
        } else {
            #pragma unroll
            for (int k = 0; k < NB_; ++k) {
                float pv = pp[k] * syn_decay[n * NB_ + k]
                         + (0.0f + x[k]) * psc_initial[n * NB_ + k];
                pp[k] = pv;
                ic += pv;
            }
        }

        unsigned pwd = zrow_prev[n >> 5];
        float pz = ((pwd >> (n & 31)) & 1u) ? 1.0f : 0.0f;

        float a0 = P1.w * asc[2 * n]     + pz * P2.y;
        float a1 = P2.x * asc[2 * n + 1] + pz * P2.z;
        asc[2 * n]     = a0;
        asc[2 * n + 1] = a1;

        float c1 = ic + (a0 + a1) + P0.z;
        float nv = P0.x * v[n] + P0.y * c1;
        if (pz > 0.5f) nv = P1.x;

        float vsc = (nv - P0.w) / P1.y;
        z = (vsc > 0.0f) ? 1.0f : 0.0f;
        float rr = r[n];
        if (rr > 0.0f) z = 0.0f;

        r[n] = fmaxf(rr + z * P1.z - 1.0f, 0.0f);   // DT = 1.0
        v[n] = nv;
        out_t[n] = z;
    }

    unsigned long long m = __ballot(z != 0.0f);
    int gtid = blockIdx.x * blockDim.x + threadIdx.x;
    int wv = gtid >> 6;
    if ((threadIdx.x & 63) == 0 && (wv << 6) < N) {
        *(unsigned long long*)(zrow_new + (wv << 1)) = m;
        if (m) atomicAdd(scnt_new, __popcll(m));
    }
}

// ---------------------------------------------------------------------------
// Launcher
// ---------------------------------------------------------------------------

extern "C" void kernel_launch(void* const* d_in, const int* in_sizes, int n_in,
                              void* d_out, int out_size, void* d_ws, size_t ws_size,
                              hipStream_t stream)
{
    const float* weights        = (const float*)d_in[0];
    const float* edge_basis     = (const float*)d_in[1];
    const float* ext_input      = (const float*)d_in[2];
    const float* decay          = (const float*)d_in[3];
    const float* current_factor = (const float*)d_in[4];
    const float* gathered_g     = (const float*)d_in[5];
    const float* v_th           = (const float*)d_in[6];
    const float* v_reset        = (const float*)d_in[7];
    const float* normalizer     = (const float*)d_in[8];
    const float* t_ref          = (const float*)d_in[9];
    const float* exp_dt_k       = (const float*)d_in[10];
    const float* asc_amps       = (const float*)d_in[11];
    const float* syn_decay      = (const float*)d_in[12];
    const float* psc_initial    = (const float*)d_in[13];
    const int*   pre_idx        = (const int*)d_in[14];
    const int*   post_idx       = (const int*)d_in[15];

    const int E  = in_sizes[0];
    const int N  = in_sizes[3];
    const int n5 = N * NB_;
    const int T  = in_sizes[2] / n5;            // B = 1

    const int words64   = (N + 63) / 64;        // 782
    const int words32   = words64 * 2;          // 1564
    const int bitstride = words32 * 32;         // 50048
    const int NS        = MD_ * bitstride;      // 250240
    const int NC        = (NS + CSLOTS - 1) / CSLOTS;   // 489

    float* out = (float*)d_out;

    // ---- workspace layout --------------------------------------------------
    char* wsb = (char*)d_ws;
    size_t o = 0;
    // zero group:
    int*   chist = (int*)(wsb + o);   o += 512 * 4;
    float* i_rec = (float*)(wsb + o); o += (size_t)n5 * 4;
    float* psc   = (float*)(wsb + o); o += (size_t)n5 * 4;
    float* r     = (float*)(wsb + o); o += (size_t)N * 4;
    float* asc   = (float*)(wsb + o); o += (size_t)2 * N * 4;
    int*   scnt  = (int*)(wsb + o);   o += (size_t)(T + MD_) * 4;
    o = (o + 15) & ~(size_t)15;
    unsigned* zbits = (unsigned*)(wsb + o);
    size_t zero_bytes = o + (size_t)MD_ * words32 * 4;
    o += (size_t)(T + MD_) * words32 * 4;
    // non-zeroed:
    o = (o + 15) & ~(size_t)15;
    float*  v           = (float*)(wsb + o);  o += (size_t)N * 4;
    float4* pk          = (float4*)(wsb + o); o += (size_t)N * 12 * 4;
    int*    row_ptr     = (int*)(wsb + o);    o += (size_t)NS * 4;
    int*    coarse_base = (int*)(wsb + o);    o += 513 * 4;
    int*    coarse_ptr  = (int*)(wsb + o);    o += 512 * 4;
    o = (o + 31) & ~(size_t)31;
    uint4*  part        = (uint4*)(wsb + o);  o += (size_t)E * 32;
    uint4*  edgeDat     = (uint4*)(wsb + o);  o += (size_t)E * 32;

    // ---- build (every launch) ----------------------------------------------
    hipMemsetAsync(d_ws, 0, zero_bytes, stream);

    repack_kernel<<<(N + 255) / 256, 256, 0, stream>>>(
        decay, current_factor, gathered_g, v_th, v_reset, normalizer, t_ref,
        exp_dt_k, asc_amps, v_reset, pk, v, N);

    const int nbe = (E + CH - 1) / CH;   // 245
    coarse_hist_kernel<<<nbe, 256, 0, stream>>>(pre_idx, chist, E, N, bitstride);
    scan_coarse_kernel<<<1, 256, 0, stream>>>(chist, coarse_base, coarse_ptr, NC);
    partition_kernel<<<nbe, 256, 0, stream>>>(
        pre_idx, weights, post_idx, edge_basis, coarse_ptr, part, E, N, bitstride);
    bucket_sort_kernel<<<NC, 256, 0, stream>>>(coarse_base, part, edgeDat, row_ptr, NS);

    // ---- time loop ----------------------------------------------------------
    const int sblk = (NS + 255) / 256;   // 978
    const int nblk = (N + 255) / 256;    // 196
    for (int t = 0; t < T; ++t) {
        edge_step_kernel<<<sblk, 256, 0, stream>>>(
            zbits + (size_t)t * words32, row_ptr, edgeDat, i_rec, scnt + t, NS);

        neuron_kernel<<<nblk, 256, 0, stream>>>(
            ext_input + (size_t)t * n5,
            psc, i_rec, syn_decay, psc_initial,
            pk, v, r, asc,
            scnt + t, scnt + t + MD_,
            zbits + (size_t)(t + MD_ - 1) * words32,
            zbits + (size_t)(t + MD_) * words32,
            out + (size_t)t * N,
            N);
    }
}